// Round 9
// baseline (95.367 us; speedup 1.0000x reference)
//
#include <hip/hip_runtime.h>
#include <hip/hip_bf16.h>
#include <math.h>

// Problem constants (from setup_inputs / reference)
#define CLASSES     5
#define C_DIM       64
#define HW          441            // 21*21
#define B_ANCH      32
#define NSUP        25             // L*S support images
#define NROWS       (B_ANCH*HW)    // 14112 query rows
#define MSUP        (NSUP*HW)      // 11025 support descriptors
#define PER_CLS     (MSUP/CLASSES) // 2205 per class
#define PER_CLS_PAD 2304           // 72 halves of 32 cols
#define NPAD        (PER_CLS_PAD - PER_CLS) // 99 zero-filled pad rows/class
#define ROW_BYTES   (C_DIM*2)      // 128 B per bf16 descriptor row
#define HALF_BYTES  (32*ROW_BYTES) // 4 KB per 32-col half-tile
#define QUARTERS    4              // column splits per class (grid.y = 5*4)
#define ROWS_PER_BLK 128           // 4 waves x 32 rows (M_rep=2)
#define NBLK_X      ((NROWS + ROWS_PER_BLK - 1) / ROWS_PER_BLK)  // 111

#define NEG_INF  (-1e30f)

typedef __bf16 bf16x8 __attribute__((ext_vector_type(8)));
typedef float  f32x4  __attribute__((ext_vector_type(4)));

// top-3 insert via med3: 3 independent ops; t0 >= t1 >= t2 invariant.
#define TOP3_INS(v, t0, t1, t2) do {                              \
    float _v = (v);                                               \
    float _n0 = fmaxf(_v, (t0));                                  \
    float _n1 = __builtin_amdgcn_fmed3f(_v, (t0), (t1));          \
    float _n2 = __builtin_amdgcn_fmed3f(_v, (t1), (t2));          \
    (t0) = _n0; (t1) = _n1; (t2) = _n2; } while (0)

// Merge two SORTED triples (u desc, v desc) -> u = top-3 of union. 6 ops.
// Verified: top1=max(u0,v0); top2=med3(u0,v0,max(u1,v1));
// top3=med3(min(u0,v0), max(u1,v1), max(u2,v2)).
#define TRIPLE_MERGE(u0, u1, u2, v0, v1, v2) do {                 \
    float _A = fminf((u0), (v0));                                 \
    float _B = fmaxf((u1), (v1));                                 \
    float _E = fmaxf((u2), (v2));                                 \
    float _m0 = fmaxf((u0), (v0));                                \
    float _m1 = __builtin_amdgcn_fmed3f((u0), (v0), _B);          \
    float _m2 = __builtin_amdgcn_fmed3f(_A, _B, _E);              \
    (u0) = _m0; (u1) = _m1; (u2) = _m2; } while (0)

// ---------------------------------------------------------------------------
// Kernel 1: L2-normalize all rows (support + anchor) into row-major bf16.
// Support -> sb with per-class row stride PER_CLS_PAD; pad rows zero-filled.
// ---------------------------------------------------------------------------
__global__ __launch_bounds__(256) void norm_rows_kernel(
    const float* __restrict__ anchor, const float* __restrict__ support,
    __bf16* __restrict__ qb, __bf16* __restrict__ sb) {
    int r = blockIdx.x * 256 + threadIdx.x;
    const int total_main = MSUP + NROWS;
    if (r >= total_main) {
        int i = r - total_main;                    // pad-row zero fill
        if (i < CLASSES * NPAD) {
            int cls = i / NPAD, ix = PER_CLS + i % NPAD;
            __bf16* op = sb + ((size_t)cls * PER_CLS_PAD + ix) * C_DIM;
            bf16x8 z = {};
            #pragma unroll
            for (int c0 = 0; c0 < C_DIM; c0 += 8) *(bf16x8*)(op + c0) = z;
        }
        return;
    }
    bool isSup = r < MSUP;
    int rc = isSup ? r : r - MSUP;
    const float* in = isSup ? support : anchor;
    int img = rc / HW, p = rc % HW;
    const float* base = in + (size_t)img * C_DIM * HW + p;
    float q[C_DIM];
    float ss = 0.f;
    #pragma unroll
    for (int c = 0; c < C_DIM; ++c) { q[c] = base[c * HW]; ss += q[c] * q[c]; }
    float sc = rsqrtf(ss);
    __bf16* op;
    if (isSup) {
        int cls = rc / PER_CLS, ix = rc - cls * PER_CLS;
        op = sb + ((size_t)cls * PER_CLS_PAD + ix) * C_DIM;
    } else {
        op = qb + (size_t)rc * C_DIM;
    }
    #pragma unroll
    for (int c0 = 0; c0 < C_DIM; c0 += 8) {
        bf16x8 v;
        #pragma unroll
        for (int j = 0; j < 8; ++j) v[j] = (__bf16)(q[c0 + j] * sc);
        *(bf16x8*)(op + c0) = v;
    }
}

// ---------------------------------------------------------------------------
// Wave-private scan of one column-quarter: NH half-tiles of 32 cols, loaded
// DIRECTLY global->VGPR (per-lane permuted address = B-fragment layout; one
// dwordx4 per fragment). 3 named register slots, 2-halves-ahead pipeline;
// the compiler inserts counted s_waitcnt vmcnt(N) before each slot's use.
// No LDS, no barriers — waves are fully independent.
// hb already includes the per-lane permutation (lr*128 + kg*16).
// TAIL: last half is class cols 2176-2207 (cf0 full; cf1 valid iff lr<13).
// ---------------------------------------------------------------------------
template<int NH, bool TAIL>
__device__ __forceinline__ void scan_quarter(
    const char* __restrict__ hb, int lr,
    const bf16x8 a0[2], const bf16x8 a1[2],
    float t0[2][4], float t1[2][4], float t2[2][4]) {
    const f32x4 z = {0.f, 0.f, 0.f, 0.f};
    bf16x8 B0[4], B1[4], B2[4];   // named slots; constant indices only

    auto load_half = [&](bf16x8 (&d)[4], int h) {
        #pragma unroll
        for (int f = 0; f < 4; ++f)
            d[f] = *(const bf16x8*)(hb + (size_t)h * HALF_BYTES
                                      + (f >> 1) * 2048 + (f & 1) * 64);
    };
    auto comp_half = [&](const bf16x8 (&s)[4], int h) {
        #pragma unroll
        for (int cf = 0; cf < 2; ++cf) {
            bool masked = TAIL && (h == NH - 1) && (cf == 1);
            #pragma unroll
            for (int r = 0; r < 2; ++r) {
                f32x4 acc = __builtin_amdgcn_mfma_f32_16x16x32_bf16(
                    a0[r], s[cf * 2 + 0], z, 0, 0, 0);
                acc = __builtin_amdgcn_mfma_f32_16x16x32_bf16(
                    a1[r], s[cf * 2 + 1], acc, 0, 0, 0);
                if (masked) {
                    bool valid = lr < 13;
                    #pragma unroll
                    for (int j = 0; j < 4; ++j) {
                        float v = valid ? acc[j] : NEG_INF;
                        TOP3_INS(v, t0[r][j], t1[r][j], t2[r][j]);
                    }
                } else {
                    #pragma unroll
                    for (int j = 0; j < 4; ++j)
                        TOP3_INS(acc[j], t0[r][j], t1[r][j], t2[r][j]);
                }
            }
        }
    };

    load_half(B0, 0);
    load_half(B1, 1);
    #pragma unroll
    for (int h = 0; h < NH; ++h) {
        switch (h % 3) {                       // h compile-time -> folds
            case 0: if (h + 2 < NH) load_half(B2, h + 2); comp_half(B0, h); break;
            case 1: if (h + 2 < NH) load_half(B0, h + 2); comp_half(B1, h); break;
            default:if (h + 2 < NH) load_half(B1, h + 2); comp_half(B2, h); break;
        }
    }
}

// ---------------------------------------------------------------------------
// Kernel 2: MFMA GEMM + partial top-3 per (row, class, quarter).
// Grid (111, 20), block 256 = 4 independent waves; wave owns 32 rows.
// Quarter q covers class halves {18q .. 18q+17}; q=3 processes 15 (rest pad).
// part layout: [row][cls][quarter][3] (raw sims; sigmoid deferred, monotone).
// A/B frag: row/col = lane&15, k = (lane>>4)*8+[0..7].
// C/D: col = lane&15, row = (lane>>4)*4 + reg.   (validated rounds 2-8)
// ---------------------------------------------------------------------------
__global__ __launch_bounds__(256) void knn_mfma_kernel(
    const __bf16* __restrict__ qb, const __bf16* __restrict__ sb,
    float* __restrict__ part) {
    int lane = threadIdx.x & 63;
    int w    = threadIdx.x >> 6;
    int lr   = lane & 15;
    int kg   = lane >> 4;
    int cls  = blockIdx.y >> 2;
    int q    = blockIdx.y & 3;
    int rowbase = blockIdx.x * ROWS_PER_BLK + w * 32;

    bf16x8 a0[2], a1[2];
    #pragma unroll
    for (int r = 0; r < 2; ++r) {
        int arow = rowbase + r * 16 + lr;
        int arc  = arow < NROWS ? arow : NROWS - 1;
        const bf16x8* qrow = (const bf16x8*)(qb + (size_t)arc * C_DIM);
        a0[r] = qrow[kg];
        a1[r] = qrow[4 + kg];
    }

    float t0[2][4], t1[2][4], t2[2][4];
    #pragma unroll
    for (int r = 0; r < 2; ++r)
        #pragma unroll
        for (int j = 0; j < 4; ++j) {
            t0[r][j] = NEG_INF; t1[r][j] = NEG_INF; t2[r][j] = NEG_INF;
        }

    const char* hb = (const char*)sb
        + (size_t)cls * PER_CLS_PAD * ROW_BYTES
        + (size_t)q * 18 * HALF_BYTES
        + lr * ROW_BYTES + kg * 16;            // per-lane fragment permute

    if (q == 3)
        scan_quarter<15, true >(hb, lr, a0, a1, t0, t1, t2);
    else
        scan_quarter<18, false>(hb, lr, a0, a1, t0, t1, t2);

    // Merge top-3 across the 16 column-lanes per row (sorted-triple butterfly)
    #pragma unroll
    for (int r = 0; r < 2; ++r) {
        #pragma unroll
        for (int j = 0; j < 4; ++j) {
            float u0 = t0[r][j], u1 = t1[r][j], u2 = t2[r][j];
            #pragma unroll
            for (int off = 1; off < 16; off <<= 1) {
                float v0 = __shfl_xor(u0, off, 64);
                float v1 = __shfl_xor(u1, off, 64);
                float v2 = __shfl_xor(u2, off, 64);
                TRIPLE_MERGE(u0, u1, u2, v0, v1, v2);
            }
            int row = rowbase + r * 16 + kg * 4 + j;
            if (lr == 0 && row < NROWS) {
                float* pp = part +
                    ((size_t)(row * CLASSES + cls) * QUARTERS + q) * 3;
                pp[0] = u0; pp[1] = u1; pp[2] = u2;
            }
        }
    }
}

// ---------------------------------------------------------------------------
// Kernel 3: merge quarter partial top-3s, sigmoid, reduce over 441 locations.
// ---------------------------------------------------------------------------
__global__ __launch_bounds__(64) void merge_reduce_kernel(
    const float* __restrict__ part, float* __restrict__ out) {
    int bl = blockIdx.x;
    int b = bl / CLASSES;
    int l = bl % CLASSES;
    int lane = threadIdx.x;
    float acc = 0.f;
    for (int p = lane; p < HW; p += 64) {
        int row = b * HW + p;
        const float* pp = part + (size_t)(row * CLASSES + l) * (QUARTERS * 3);
        float u0 = pp[0], u1 = pp[1], u2 = pp[2];
        TRIPLE_MERGE(u0, u1, u2, pp[3], pp[4],  pp[5]);
        TRIPLE_MERGE(u0, u1, u2, pp[6], pp[7],  pp[8]);
        TRIPLE_MERGE(u0, u1, u2, pp[9], pp[10], pp[11]);
        acc += 1.f / (1.f + __expf(-u0))
             + 1.f / (1.f + __expf(-u1))
             + 1.f / (1.f + __expf(-u2));
    }
    #pragma unroll
    for (int off = 32; off; off >>= 1) acc += __shfl_xor(acc, off, 64);
    if (lane == 0) out[bl] = acc;
}

// ---------------------------------------------------------------------------
extern "C" void kernel_launch(void* const* d_in, const int* in_sizes, int n_in,
                              void* d_out, int out_size, void* d_ws, size_t ws_size,
                              hipStream_t stream) {
    const float* anchor  = (const float*)d_in[0];
    const float* support = (const float*)d_in[1];
    // d_in[2]=av_num(1), d_in[3]=sav_num(1) -- fixed by setup, ignored.

    // ws: sb bf16[5*2304*64] | qb bf16[NROWS*64] | part f32[NROWS*5*4*3]
    __bf16* sb = (__bf16*)d_ws;
    __bf16* qb = sb + (size_t)CLASSES * PER_CLS_PAD * C_DIM;
    float* part = (float*)(qb + (size_t)NROWS * C_DIM);

    {
        int total = MSUP + NROWS + CLASSES * NPAD;
        dim3 g((total + 255) / 256);
        norm_rows_kernel<<<g, 256, 0, stream>>>(anchor, support, qb, sb);
    }
    {
        dim3 g(NBLK_X, CLASSES * QUARTERS);
        knn_mfma_kernel<<<g, 256, 0, stream>>>(qb, sb, part);
    }
    {
        dim3 gm(B_ANCH * CLASSES);
        merge_reduce_kernel<<<gm, 64, 0, stream>>>(part, (float*)d_out);
    }
}

// Round 10
// 54.869 us; speedup vs baseline: 1.7381x; 1.7381x over previous
//
#include <hip/hip_runtime.h>
#include <hip/hip_bf16.h>
#include <math.h>

// Problem constants (from setup_inputs / reference)
#define CLASSES     5
#define C_DIM       64
#define HW          441            // 21*21
#define B_ANCH      32
#define NSUP        25             // L*S support images
#define NROWS       (B_ANCH*HW)    // 14112 query rows
#define MSUP        (NSUP*HW)      // 11025 support descriptors
#define PER_CLS     (MSUP/CLASSES) // 2205 per class
#define TILE_COLS   64
#define PER_CLS_PAD 2304           // 36 tiles of 64
#define NPAD        (PER_CLS_PAD - PER_CLS) // 99 zero-filled pad rows/class
#define ROW_BYTES   (C_DIM*2)      // 128 B per bf16 descriptor row
#define QUARTERS    4              // column splits per class (grid.y = 5*4)
#define ROWS_PER_BLK 128           // 4 waves x 32 rows (M_rep=2)
#define NBLK_X      ((NROWS + ROWS_PER_BLK - 1) / ROWS_PER_BLK)  // 111

#define NEG_INF  (-1e30f)

typedef __bf16 bf16x8 __attribute__((ext_vector_type(8)));
typedef float  f32x4  __attribute__((ext_vector_type(4)));

// top-3 insert via med3: 3 independent ops; t0 >= t1 >= t2 invariant.
#define TOP3_INS(v, t0, t1, t2) do {                              \
    float _v = (v);                                               \
    float _n0 = fmaxf(_v, (t0));                                  \
    float _n1 = __builtin_amdgcn_fmed3f(_v, (t0), (t1));          \
    float _n2 = __builtin_amdgcn_fmed3f(_v, (t1), (t2));          \
    (t0) = _n0; (t1) = _n1; (t2) = _n2; } while (0)

// Merge two SORTED triples (u desc, v desc) -> u = top-3 of union. 6 ops.
// Field-validated round 9 (absmax 0).
#define TRIPLE_MERGE(u0, u1, u2, v0, v1, v2) do {                 \
    float _A = fminf((u0), (v0));                                 \
    float _B = fmaxf((u1), (v1));                                 \
    float _E = fmaxf((u2), (v2));                                 \
    float _m0 = fmaxf((u0), (v0));                                \
    float _m1 = __builtin_amdgcn_fmed3f((u0), (v0), _B);          \
    float _m2 = __builtin_amdgcn_fmed3f(_A, _B, _E);              \
    (u0) = _m0; (u1) = _m1; (u2) = _m2; } while (0)

typedef __attribute__((address_space(1))) const void g_void;
typedef __attribute__((address_space(3))) void l_void;
__device__ __forceinline__ void gload_lds16(const void* g, void* l) {
    __builtin_amdgcn_global_load_lds((g_void*)g, (l_void*)l, 16, 0, 0);
}

// ---------------------------------------------------------------------------
// Kernel 1: L2-normalize all rows (support + anchor) into row-major bf16.
// Support -> sb with per-class row stride PER_CLS_PAD; pad rows zero-filled.
// ---------------------------------------------------------------------------
__global__ __launch_bounds__(256) void norm_rows_kernel(
    const float* __restrict__ anchor, const float* __restrict__ support,
    __bf16* __restrict__ qb, __bf16* __restrict__ sb) {
    int r = blockIdx.x * 256 + threadIdx.x;
    const int total_main = MSUP + NROWS;
    if (r >= total_main) {
        int i = r - total_main;                    // pad-row zero fill
        if (i < CLASSES * NPAD) {
            int cls = i / NPAD, ix = PER_CLS + i % NPAD;
            __bf16* op = sb + ((size_t)cls * PER_CLS_PAD + ix) * C_DIM;
            bf16x8 z = {};
            #pragma unroll
            for (int c0 = 0; c0 < C_DIM; c0 += 8) *(bf16x8*)(op + c0) = z;
        }
        return;
    }
    bool isSup = r < MSUP;
    int rc = isSup ? r : r - MSUP;
    const float* in = isSup ? support : anchor;
    int img = rc / HW, p = rc % HW;
    const float* base = in + (size_t)img * C_DIM * HW + p;
    float q[C_DIM];
    float ss = 0.f;
    #pragma unroll
    for (int c = 0; c < C_DIM; ++c) { q[c] = base[c * HW]; ss += q[c] * q[c]; }
    float sc = rsqrtf(ss);
    __bf16* op;
    if (isSup) {
        int cls = rc / PER_CLS, ix = rc - cls * PER_CLS;
        op = sb + ((size_t)cls * PER_CLS_PAD + ix) * C_DIM;
    } else {
        op = qb + (size_t)rc * C_DIM;
    }
    #pragma unroll
    for (int c0 = 0; c0 < C_DIM; c0 += 8) {
        bf16x8 v;
        #pragma unroll
        for (int j = 0; j < 8; ++j) v[j] = (__bf16)(q[c0 + j] * sc);
        *(bf16x8*)(op + c0) = v;
    }
}

// ---------------------------------------------------------------------------
// Fully-unrolled GEMM+top3 over one column-quarter (QNT tiles of 64 cols).
// Compute is split into two decoupled streams per tile: (1) all 16 MFMAs
// into 8 distinct f32x4 accumulators (pure matrix-pipe cluster, setprio'd),
// (2) all 96 TOP3 VALU ops. No MFMA->VALU->MFMA ping-pong: by the time the
// last MFMA issues, the first results have retired.
// TAIL=true: last tile is class cols 2176-2239 (s=0 full, s=1 iff lr<13,
// s=2,3 all-pad -> skipped).
// ---------------------------------------------------------------------------
template<int QNT, bool TAIL>
__device__ __forceinline__ void gemm_quarter(
    const char* qbase,            // sbCls + quarter offset
    char* smem_base,              // 3 x 8KB LDS buffers
    int laneOff,                  // lr*128 + kg*16 (per-lane source permute)
    int pr0, int lane, int lr,
    const bf16x8 a0[2], const bf16x8 a1[2],
    float t0[2][4], float t1[2][4], float t2[2][4]) {

    auto stage = [&](int buf, int tt) {
        const char* tb = qbase + tt * (TILE_COLS * ROW_BYTES);
        #pragma unroll
        for (int i = 0; i < 2; ++i) {
            int pr = pr0 + 4 * i;                          // wave-uniform
            gload_lds16(tb + ((pr >> 1) * 2048 + (pr & 1) * 64) + laneOff,
                        smem_base + buf * 8192 + pr * 1024);
        }
    };

    const bf16x8* sm = (const bf16x8*)smem_base;   // [3][4][2][64]
    const f32x4 z = {0.f, 0.f, 0.f, 0.f};

    stage(0, 0);
    stage(1, 1);
    #pragma unroll
    for (int tt = 0; tt < QNT; ++tt) {
        if (tt < QNT - 1) asm volatile("s_waitcnt vmcnt(2)" ::: "memory");
        else              asm volatile("s_waitcnt vmcnt(0)" ::: "memory");
        __builtin_amdgcn_s_barrier();
        if (tt + 2 < QNT) stage((tt + 2) % 3, tt + 2);
        const int buf = tt % 3;
        const bool tail = TAIL && (tt == QNT - 1);
        if (!tail) {
            bf16x8 b[8];
            #pragma unroll
            for (int s = 0; s < 4; ++s) {                 // 8 reads in flight
                b[2*s]   = sm[((buf*4 + s)*2 + 0)*64 + lane];
                b[2*s+1] = sm[((buf*4 + s)*2 + 1)*64 + lane];
            }
            // Stream 1: pure MFMA cluster into 8 independent accumulators
            f32x4 acc[8];
            __builtin_amdgcn_s_setprio(1);
            #pragma unroll
            for (int s = 0; s < 4; ++s)
                #pragma unroll
                for (int r = 0; r < 2; ++r) {
                    acc[s*2+r] = __builtin_amdgcn_mfma_f32_16x16x32_bf16(
                        a0[r], b[2*s], z, 0, 0, 0);
                    acc[s*2+r] = __builtin_amdgcn_mfma_f32_16x16x32_bf16(
                        a1[r], b[2*s+1], acc[s*2+r], 0, 0, 0);
                }
            __builtin_amdgcn_s_setprio(0);
            // Stream 2: all TOP3 inserts (8 independent chains, issue-bound)
            #pragma unroll
            for (int s = 0; s < 4; ++s)
                #pragma unroll
                for (int r = 0; r < 2; ++r)
                    #pragma unroll
                    for (int j = 0; j < 4; ++j)
                        TOP3_INS(acc[s*2+r][j], t0[r][j], t1[r][j], t2[r][j]);
        } else {
            // class tile 34: cols 2176+s*16+lr; s=0 full, s=1 iff lr<13
            bf16x8 b[4];
            #pragma unroll
            for (int s = 0; s < 2; ++s) {
                b[2*s]   = sm[((buf*4 + s)*2 + 0)*64 + lane];
                b[2*s+1] = sm[((buf*4 + s)*2 + 1)*64 + lane];
            }
            f32x4 acc[4];
            __builtin_amdgcn_s_setprio(1);
            #pragma unroll
            for (int s = 0; s < 2; ++s)
                #pragma unroll
                for (int r = 0; r < 2; ++r) {
                    acc[s*2+r] = __builtin_amdgcn_mfma_f32_16x16x32_bf16(
                        a0[r], b[2*s], z, 0, 0, 0);
                    acc[s*2+r] = __builtin_amdgcn_mfma_f32_16x16x32_bf16(
                        a1[r], b[2*s+1], acc[s*2+r], 0, 0, 0);
                }
            __builtin_amdgcn_s_setprio(0);
            #pragma unroll
            for (int s = 0; s < 2; ++s) {
                bool valid = (s == 0) || (lr < 13);   // SELECT: pads stay out
                #pragma unroll
                for (int r = 0; r < 2; ++r)
                    #pragma unroll
                    for (int j = 0; j < 4; ++j) {
                        float v = valid ? acc[s*2+r][j] : NEG_INF;
                        TOP3_INS(v, t0[r][j], t1[r][j], t2[r][j]);
                    }
            }
        }
    }
}

// ---------------------------------------------------------------------------
// Kernel 2: MFMA GEMM + partial top-3 per (row, class, quarter).
// Grid (111, 20), block 256 = 4 waves; wave owns 32 rows (M_rep=2).
// B staged to LDS fragment-major (pre-permuted global source, linear LDS
// dest -> conflict-free ds_read_b128); 3 buffers, counted vmcnt(2).
// __launch_bounds__(256,4): license ~128 VGPRs (LDS caps residency anyway)
// so the compiler can keep 8 acc tiles + 8 B-frags live without serializing.
// A/B frag: row/col = lane&15, k = (lane>>4)*8+[0..7].
// C/D: col = lane&15, row = (lane>>4)*4 + reg.   (validated rounds 2-9)
// ---------------------------------------------------------------------------
__global__ __launch_bounds__(256, 4) void knn_mfma_kernel(
    const __bf16* __restrict__ qb, const __bf16* __restrict__ sb,
    float* __restrict__ part) {
    __shared__ bf16x8 smem[3][4][2][64];   // 24 KB

    int lane = threadIdx.x & 63;
    int w    = threadIdx.x >> 6;
    int lr   = lane & 15;
    int kg   = lane >> 4;
    int cls  = blockIdx.y >> 2;
    int q    = blockIdx.y & 3;
    int rowbase = blockIdx.x * ROWS_PER_BLK + w * 32;

    bf16x8 a0[2], a1[2];
    #pragma unroll
    for (int r = 0; r < 2; ++r) {
        int arow = rowbase + r * 16 + lr;
        int arc  = arow < NROWS ? arow : NROWS - 1;
        const bf16x8* qrow = (const bf16x8*)(qb + (size_t)arc * C_DIM);
        a0[r] = qrow[kg];
        a1[r] = qrow[4 + kg];
    }

    float t0[2][4], t1[2][4], t2[2][4];
    #pragma unroll
    for (int r = 0; r < 2; ++r)
        #pragma unroll
        for (int j = 0; j < 4; ++j) {
            t0[r][j] = NEG_INF; t1[r][j] = NEG_INF; t2[r][j] = NEG_INF;
        }

    const char* qbase = (const char*)sb
        + (size_t)cls * PER_CLS_PAD * ROW_BYTES
        + (size_t)q * 9 * (TILE_COLS * ROW_BYTES);
    int laneOff = lr * ROW_BYTES + kg * 16;

    if (q == 3)
        gemm_quarter<8, true >(qbase, (char*)smem, laneOff, w, lane, lr,
                               a0, a1, t0, t1, t2);
    else
        gemm_quarter<9, false>(qbase, (char*)smem, laneOff, w, lane, lr,
                               a0, a1, t0, t1, t2);

    // Merge top-3 across the 16 column-lanes per row (sorted-triple butterfly)
    #pragma unroll
    for (int r = 0; r < 2; ++r) {
        #pragma unroll
        for (int j = 0; j < 4; ++j) {
            float u0 = t0[r][j], u1 = t1[r][j], u2 = t2[r][j];
            #pragma unroll
            for (int off = 1; off < 16; off <<= 1) {
                float v0 = __shfl_xor(u0, off, 64);
                float v1 = __shfl_xor(u1, off, 64);
                float v2 = __shfl_xor(u2, off, 64);
                TRIPLE_MERGE(u0, u1, u2, v0, v1, v2);
            }
            int row = rowbase + r * 16 + kg * 4 + j;
            if (lr == 0 && row < NROWS) {
                float* pp = part +
                    ((size_t)(row * CLASSES + cls) * QUARTERS + q) * 3;
                pp[0] = u0; pp[1] = u1; pp[2] = u2;
            }
        }
    }
}

// ---------------------------------------------------------------------------
// Kernel 3: merge quarter partial top-3s, sigmoid, reduce over 441 locations.
// ---------------------------------------------------------------------------
__global__ __launch_bounds__(64) void merge_reduce_kernel(
    const float* __restrict__ part, float* __restrict__ out) {
    int bl = blockIdx.x;
    int b = bl / CLASSES;
    int l = bl % CLASSES;
    int lane = threadIdx.x;
    float acc = 0.f;
    for (int p = lane; p < HW; p += 64) {
        int row = b * HW + p;
        const float* pp = part + (size_t)(row * CLASSES + l) * (QUARTERS * 3);
        float u0 = pp[0], u1 = pp[1], u2 = pp[2];
        TRIPLE_MERGE(u0, u1, u2, pp[3], pp[4],  pp[5]);
        TRIPLE_MERGE(u0, u1, u2, pp[6], pp[7],  pp[8]);
        TRIPLE_MERGE(u0, u1, u2, pp[9], pp[10], pp[11]);
        acc += 1.f / (1.f + __expf(-u0))
             + 1.f / (1.f + __expf(-u1))
             + 1.f / (1.f + __expf(-u2));
    }
    #pragma unroll
    for (int off = 32; off; off >>= 1) acc += __shfl_xor(acc, off, 64);
    if (lane == 0) out[bl] = acc;
}

// ---------------------------------------------------------------------------
extern "C" void kernel_launch(void* const* d_in, const int* in_sizes, int n_in,
                              void* d_out, int out_size, void* d_ws, size_t ws_size,
                              hipStream_t stream) {
    const float* anchor  = (const float*)d_in[0];
    const float* support = (const float*)d_in[1];
    // d_in[2]=av_num(1), d_in[3]=sav_num(1) -- fixed by setup, ignored.

    // ws: sb bf16[5*2304*64] | qb bf16[NROWS*64] | part f32[NROWS*5*4*3]
    __bf16* sb = (__bf16*)d_ws;
    __bf16* qb = sb + (size_t)CLASSES * PER_CLS_PAD * C_DIM;
    float* part = (float*)(qb + (size_t)NROWS * C_DIM);

    {
        int total = MSUP + NROWS + CLASSES * NPAD;
        dim3 g((total + 255) / 256);
        norm_rows_kernel<<<g, 256, 0, stream>>>(anchor, support, qb, sb);
    }
    {
        dim3 g(NBLK_X, CLASSES * QUARTERS);
        knn_mfma_kernel<<<g, 256, 0, stream>>>(qb, sb, part);
    }
    {
        dim3 gm(B_ANCH * CLASSES);
        merge_reduce_kernel<<<gm, 64, 0, stream>>>(part, (float*)d_out);
    }
}